// Round 1
// 437.267 us; speedup vs baseline: 1.2933x; 1.2933x over previous
//
#include <hip/hip_runtime.h>
#include <cmath>

// ---------------------------------------------------------------------------
// OHDeltaProductSSM: u(8,2048,1024) -> out(8,2048,1024), fp32.
// Round 1 change: gemmA (41% of runtime, fp32 VALU, MfmaUtil=0) replaced by
// bf16 MFMA (v_mfma_f32_16x16x32_bf16) with 2-pass split precision:
//   Feat = (u_hi + u_lo) . Wb^T,  u_hi/u_lo bf16 split of u (2^-17 rel),
//   Wb = RNE-bf16 of Wp padded to 512 rows (zeros in 448..511; postA
//   overwrites Feat[.,448..512) afterwards so the pad is scratch).
// Tiled operand layout (written by convertU/convertW, staged linearly with
// global_load_lds, fragment-read with ds_read_b128):
//   tile (rowblk, kt) = 128x32 bf16, 8 KB, contiguous.
//   within tile: element (r, k): granule g=k>>2, pair p=g&3, half h=g>>2,
//   stored s' = ((p ^ ((r>>2)&3))<<1) | h, index = r*32 + s'*4 + (k&3).
//   - pair-interleave (g, g+4 adjacent) => each MFMA fragment = ONE b128.
//   - XOR by (r>>2)&3 => ~2-way LDS bank conflicts (free).
//   - identical permutation on A and B  => internal-K mapping cancels,
//     correctness independent of the exact halves-vs-contiguous K layout.
// Verified MFMA facts used: A row = lane&15, B col = lane&15,
// D: col = lane&15, row = 4*(lane>>4)+reg  [guide m89/m91].
// u_hi/u_lo (64 MB) overlay Mc/dcv/hstart/hsb (dead until after gemmA) and
// extend the workspace to ~105.4 MB; host falls back to 1-pass split or the
// old fp32 gemmA if ws_size is reported smaller.
// Everything else (postA, scanB*, gemmC) unchanged from the 561 µs version.
// ---------------------------------------------------------------------------

#define NTOK 16384
#define TT 2048
#define BB 8
#define DM 1024
#define FS 520
#define CH 32
#define LCH 64
#define NW 448   // packed weight rows (valid)
#define NWP 512  // padded to power of two for MFMA gemm

typedef short bf16x8 __attribute__((ext_vector_type(8)));
typedef float f32x4 __attribute__((ext_vector_type(4)));

#define GLOAD_LDS16(g, l)                                          \
  __builtin_amdgcn_global_load_lds(                                \
      (const __attribute__((address_space(1))) void*)(g),          \
      (__attribute__((address_space(3))) void*)(l), 16, 0, 0)

__global__ __launch_bounds__(256) void packW(
    const float* __restrict__ W_A, const float* __restrict__ b_A,
    const float* __restrict__ W_k, const float* __restrict__ b_k,
    const float* __restrict__ b_beta,
    const float* __restrict__ B_w, const float* __restrict__ B_b,
    float* __restrict__ Wp, float* __restrict__ bias) {
  int r = blockIdx.x;          // 0..447
  int tid = threadIdx.x;
  const float* src;
  float bv;
  if (r < 64)       { src = W_A + (size_t)r * DM;         bv = b_A[r]; }
  else if (r < 320) { src = W_k + (size_t)(r - 64) * DM;  bv = b_k[r - 64]; }
  else              { src = B_w + (size_t)(r - 320) * DM; bv = B_b[r - 320]; }
  ((float4*)(Wp + (size_t)r * DM))[tid] = ((const float4*)src)[tid];
  if (tid == 0) bias[r] = bv;
  if (r == 0 && tid < 2) bias[448 + tid] = b_beta[tid];
}

// generic transpose: src[M][N] -> dst[N][M], 64x64 tiles, M,N multiples of 64
__global__ __launch_bounds__(256) void transK(
    const float* __restrict__ src, float* __restrict__ dst, int M, int N) {
  __shared__ float tile[64][68];
  const int m0 = blockIdx.x * 64, n0 = blockIdx.y * 64;
  const int tid = threadIdx.x;
#pragma unroll
  for (int l = 0; l < 4; ++l) {
    int idx = tid + l * 256;
    int r = idx >> 4, c4 = (idx & 15) * 4;
    float4 v = *(const float4*)(src + (size_t)(m0 + r) * N + n0 + c4);
    tile[r][c4 + 0] = v.x; tile[r][c4 + 1] = v.y;
    tile[r][c4 + 2] = v.z; tile[r][c4 + 3] = v.w;
  }
  __syncthreads();
#pragma unroll
  for (int l = 0; l < 4; ++l) {
    int idx = tid + l * 256;
    int c = idx >> 4, r4 = (idx & 15) * 4;
    float4 w = make_float4(tile[r4 + 0][c], tile[r4 + 1][c],
                           tile[r4 + 2][c], tile[r4 + 3][c]);
    *(float4*)(dst + (size_t)(n0 + c) * M + m0 + r4) = w;
  }
}

__device__ inline unsigned short bf16_rne(float x) {
  unsigned b = __float_as_uint(x);
  b += 0x7FFFu + ((b >> 16) & 1u);
  return (unsigned short)(b >> 16);
}

__device__ inline void split_bf16(float x, unsigned short& h, unsigned short& l) {
  unsigned b = __float_as_uint(x);
  h = (unsigned short)(b >> 16);                       // truncated high part
  float rem = x - __uint_as_float(b & 0xFFFF0000u);    // exact remainder
  l = bf16_rne(rem);
}

// u fp32 -> u_hi/u_lo bf16, tiled (mb,kt) 128x32, swizzled granules.
// grid 16384 x 256: one granule (4 floats along k) per thread.
__global__ __launch_bounds__(256) void convertU(
    const float* __restrict__ u, unsigned short* __restrict__ uh,
    unsigned short* __restrict__ ul) {
  int gid = blockIdx.x * 256 + threadIdx.x;
  int m = gid >> 8;          // token row 0..16383
  int g = gid & 255;         // granule along k
  float4 v = *(const float4*)(u + (size_t)m * DM + g * 4);
  int kt = g >> 3, gg = g & 7;
  int p = gg & 3, h = gg >> 2;
  int mr = m & 127, mb = m >> 7;
  int pp = p ^ ((mr >> 2) & 3);
  size_t dst = ((size_t)(mb * 32 + kt)) * 4096 + mr * 32 + ((pp << 1) | h) * 4;
  ushort4 hi, lo;
  split_bf16(v.x, hi.x, lo.x);
  split_bf16(v.y, hi.y, lo.y);
  split_bf16(v.z, hi.z, lo.z);
  split_bf16(v.w, hi.w, lo.w);
  *(ushort4*)(uh + dst) = hi;
  *(ushort4*)(ul + dst) = lo;
}

// Wp fp32 (448 rows) -> Wb bf16 tiled (nb,kt) 128x32, rows 448..511 zero.
// grid 512 x 256.
__global__ __launch_bounds__(256) void convertW(
    const float* __restrict__ Wp, unsigned short* __restrict__ Wb) {
  int gid = blockIdx.x * 256 + threadIdx.x;
  int n = gid >> 8, g = gid & 255;
  int kt = g >> 3, gg = g & 7;
  int p = gg & 3, h = gg >> 2;
  int nr = n & 127, nb = n >> 7;
  int pp = p ^ ((nr >> 2) & 3);
  size_t dst = ((size_t)(nb * 32 + kt)) * 4096 + nr * 32 + ((pp << 1) | h) * 4;
  ushort4 hv = make_ushort4(0, 0, 0, 0);
  if (n < NW) {
    float4 v = *(const float4*)(Wp + (size_t)n * DM + g * 4);
    hv.x = bf16_rne(v.x); hv.y = bf16_rne(v.y);
    hv.z = bf16_rne(v.z); hv.w = bf16_rne(v.w);
  }
  *(ushort4*)(Wb + dst) = hv;
}

// Feat[0..512) = (u_hi + u_lo) . Wb^T via MFMA. 128x128 tile, BK=32,
// 4 waves 2x2, wave tile 64x64 (4x4 fragments of 16x16).
__global__ __launch_bounds__(256) void gemmA_mfma(
    const unsigned short* __restrict__ uh, const unsigned short* __restrict__ ul,
    const unsigned short* __restrict__ Wb, float* __restrict__ Feat, int npass) {
  __shared__ __align__(16) unsigned short As[4096];
  __shared__ __align__(16) unsigned short Bs[4096];
  const int tid = threadIdx.x;
  const int wv = tid >> 6, ln = tid & 63;
  const int lr = ln & 15, G = ln >> 4;
  const int wm = wv >> 1, wn = wv & 1;
  const int x = G ^ (lr >> 2);          // inverse of the granule XOR swizzle
  f32x4 acc[4][4];
#pragma unroll
  for (int i = 0; i < 4; ++i)
#pragma unroll
    for (int j = 0; j < 4; ++j) acc[i][j] = (f32x4){0.f, 0.f, 0.f, 0.f};

  const size_t aBase = (size_t)blockIdx.x * 32 * 4096;
  const size_t bBase = (size_t)blockIdx.y * 32 * 4096;
  const int so = wv * 512 + ln * 8;     // staging src offset (bf16 elems)
  const int ld = wv * 512;              // staging lds base (wave-uniform)

  for (int pass = 0; pass < npass; ++pass) {
    const unsigned short* ua = pass ? ul : uh;
    for (int kt = 0; kt < 32; ++kt) {
      const unsigned short* ga = ua + aBase + (size_t)kt * 4096;
      const unsigned short* gb = Wb + bBase + (size_t)kt * 4096;
      GLOAD_LDS16(ga + so,        As + ld);
      GLOAD_LDS16(ga + 2048 + so, As + 2048 + ld);
      GLOAD_LDS16(gb + so,        Bs + ld);
      GLOAD_LDS16(gb + 2048 + so, Bs + 2048 + ld);
      __syncthreads();   // compiler drains vmcnt before s_barrier
      bf16x8 af[4], bfr[4];
      const char* Ab = (const char*)As + ((wm * 64 + lr) << 6) + (x << 4);
      const char* Bb = (const char*)Bs + ((wn * 64 + lr) << 6) + (x << 4);
#pragma unroll
      for (int i = 0; i < 4; ++i) {
        af[i]  = *(const bf16x8*)(Ab + i * 1024);   // +16 rows = 1024 B
        bfr[i] = *(const bf16x8*)(Bb + i * 1024);
      }
#pragma unroll
      for (int i = 0; i < 4; ++i)
#pragma unroll
        for (int j = 0; j < 4; ++j)
          acc[i][j] = __builtin_amdgcn_mfma_f32_16x16x32_bf16(
              af[i], bfr[j], acc[i][j], 0, 0, 0);
      __syncthreads();
    }
  }
  // D layout: col = lane&15, row = 4*(lane>>4)+reg
  const int row0 = (blockIdx.x << 7) + wm * 64 + (G << 2);
  const int col0 = (blockIdx.y << 7) + wn * 64 + lr;
  float* fb = Feat + (size_t)row0 * FS + col0;
#pragma unroll
  for (int i = 0; i < 4; ++i)
#pragma unroll
    for (int j = 0; j < 4; ++j) {
      float* d = fb + (size_t)(i * 16) * FS + j * 16;
#pragma unroll
      for (int r = 0; r < 4; ++r) d[(size_t)r * FS] = acc[i][j][r];
    }
}

// ---- legacy fp32 gemmA (fallback if workspace too small) ------------------
__global__ __launch_bounds__(256) void gemmA_f32(
    const float* __restrict__ u, const float* __restrict__ WpT,
    float* __restrict__ Feat) {
  __shared__ float us2[128][36];
  __shared__ float wsm[32][68];
  const int tid = threadIdx.x;
  const int tx = tid & 15, ty = tid >> 4;
  const int m0 = blockIdx.x * 128;
  const int n0 = blockIdx.y * 64;
  float acc[8][4];
#pragma unroll
  for (int i = 0; i < 8; ++i)
#pragma unroll
    for (int j = 0; j < 4; ++j) acc[i][j] = 0.f;

  for (int k0 = 0; k0 < DM; k0 += 32) {
#pragma unroll
    for (int l = 0; l < 4; ++l) {
      int idx = tid + l * 256;
      int r = idx >> 3, c4 = (idx & 7) * 4;
      float4 v = *(const float4*)(u + (size_t)(m0 + r) * DM + k0 + c4);
      *(float4*)&us2[r][c4] = v;
    }
#pragma unroll
    for (int l = 0; l < 2; ++l) {
      int idx = tid + l * 256;
      int k = idx >> 4, c4 = (idx & 15) * 4;
      float4 v = *(const float4*)(WpT + (size_t)(k0 + k) * NW + n0 + c4);
      *(float4*)&wsm[k][c4] = v;
    }
    __syncthreads();
#pragma unroll
    for (int k4 = 0; k4 < 8; ++k4) {
      float4 bq0 = *(const float4*)&wsm[4 * k4 + 0][tx * 4];
      float4 bq1 = *(const float4*)&wsm[4 * k4 + 1][tx * 4];
      float4 bq2 = *(const float4*)&wsm[4 * k4 + 2][tx * 4];
      float4 bq3 = *(const float4*)&wsm[4 * k4 + 3][tx * 4];
#pragma unroll
      for (int i = 0; i < 8; ++i) {
        float4 a = *(const float4*)&us2[ty * 8 + i][4 * k4];
        acc[i][0] = fmaf(a.x, bq0.x, acc[i][0]);
        acc[i][1] = fmaf(a.x, bq0.y, acc[i][1]);
        acc[i][2] = fmaf(a.x, bq0.z, acc[i][2]);
        acc[i][3] = fmaf(a.x, bq0.w, acc[i][3]);
        acc[i][0] = fmaf(a.y, bq1.x, acc[i][0]);
        acc[i][1] = fmaf(a.y, bq1.y, acc[i][1]);
        acc[i][2] = fmaf(a.y, bq1.z, acc[i][2]);
        acc[i][3] = fmaf(a.y, bq1.w, acc[i][3]);
        acc[i][0] = fmaf(a.z, bq2.x, acc[i][0]);
        acc[i][1] = fmaf(a.z, bq2.y, acc[i][1]);
        acc[i][2] = fmaf(a.z, bq2.z, acc[i][2]);
        acc[i][3] = fmaf(a.z, bq2.w, acc[i][3]);
        acc[i][0] = fmaf(a.w, bq3.x, acc[i][0]);
        acc[i][1] = fmaf(a.w, bq3.y, acc[i][1]);
        acc[i][2] = fmaf(a.w, bq3.z, acc[i][2]);
        acc[i][3] = fmaf(a.w, bq3.w, acc[i][3]);
      }
    }
    __syncthreads();
  }
#pragma unroll
  for (int i = 0; i < 8; ++i) {
    float4 v = make_float4(acc[i][0], acc[i][1], acc[i][2], acc[i][3]);
    *(float4*)(Feat + (size_t)(m0 + ty * 8 + i) * FS + n0 + tx * 4) = v;
  }
}

__device__ inline float wave_sum(float v) {
#pragma unroll
  for (int off = 32; off > 0; off >>= 1) v += __shfl_xor(v, off, 64);
  return v;
}

// per-token nonlinearity, one wave per token, in-place in Feat
__global__ __launch_bounds__(64) void postA(float* __restrict__ Feat,
                                            const float* __restrict__ bias,
                                            const float* __restrict__ u,
                                            const float* __restrict__ Wb) {
  const int t = blockIdx.x, lane = threadIdx.x;
  float* f = Feat + (size_t)t * FS;
  float s0 = 0.f, s1 = 0.f;
#pragma unroll
  for (int j = 0; j < 4; ++j) {
    float4 uv = *(const float4*)(u + (size_t)t * DM + j * 256 + lane * 4);
    float4 w0 = *(const float4*)(Wb + j * 256 + lane * 4);
    float4 w1 = *(const float4*)(Wb + DM + j * 256 + lane * 4);
    s0 = fmaf(uv.x, w0.x, s0); s0 = fmaf(uv.y, w0.y, s0);
    s0 = fmaf(uv.z, w0.z, s0); s0 = fmaf(uv.w, w0.w, s0);
    s1 = fmaf(uv.x, w1.x, s1); s1 = fmaf(uv.y, w1.y, s1);
    s1 = fmaf(uv.z, w1.z, s1); s1 = fmaf(uv.w, w1.w, s1);
  }
  s0 = wave_sum(s0); s1 = wave_sum(s1);
  float a = f[lane] + bias[lane];
  a = fminf(fmaxf(a, 0.f), 100.f);
  float S = 1.f / (1.f + 0.01f * a);
  f[lane] = S;
  f[448 + lane] = 0.1f * a * S;
  float k10 = f[64 + lane] + bias[64 + lane];
  float k11 = f[128 + lane] + bias[128 + lane];
  float n1 = wave_sum(k10 * k10 + k11 * k11);
  float inv1 = 1.f / fmaxf(sqrtf(n1), 1e-12f);
  k10 *= inv1; k11 *= inv1;
  f[64 + lane] = k10; f[128 + lane] = k11;
  float k20 = f[192 + lane] + bias[192 + lane];
  float k21 = f[256 + lane] + bias[256 + lane];
  float n2 = wave_sum(k20 * k20 + k21 * k21);
  float inv2 = 1.f / fmaxf(sqrtf(n2), 1e-12f);
  k20 *= inv2; k21 *= inv2;
  f[192 + lane] = k20; f[256 + lane] = k21;
  float c12 = wave_sum(k10 * k20 + k11 * k21);
  if (lane == 0) {
    f[512] = 2.f / (1.f + expf(-(s0 + bias[448])));
    f[513] = 2.f / (1.f + expf(-(s1 + bias[449])));
    f[514] = c12;
  }
  f[320 + lane] += bias[320 + lane];
  f[384 + lane] += bias[384 + lane];
}

// chunk transition matrices. 512 threads: col = tid>>2, quarter q = tid&3.
__global__ __launch_bounds__(512, 2) void scanB1(
    const float* __restrict__ Feat, float* __restrict__ Mc) {
  const int cid = blockIdx.x;              // 0..255 = b*32 + chunk
  const int t0 = (cid >> 5) * TT + (cid & 31) * LCH;
  const int tid = threadIdx.x;
  const int col = tid >> 2, q = tid & 3;
  const int i0 = q * 16;
  __shared__ float fb[2][4 * FS];
  float mz[16], my[16];
#pragma unroll
  for (int j = 0; j < 16; ++j) {
    mz[j] = (i0 + j == col) ? 1.f : 0.f;
    my[j] = (64 + i0 + j == col) ? 1.f : 0.f;
  }
  {
    const float4* src = (const float4*)(Feat + (size_t)t0 * FS);
    for (int v = tid; v < FS; v += 512) ((float4*)fb[0])[v] = src[v];
  }
  __syncthreads();
  for (int g = 0; g < 16; ++g) {
    const int cur = g & 1;
    float4 pf0, pf1;
    const bool has2 = tid < (FS - 512);
    if (g < 15) {
      const float4* src = (const float4*)(Feat + (size_t)(t0 + (g + 1) * 4) * FS);
      pf0 = src[tid];
      if (has2) pf1 = src[tid + 512];
    }
#pragma unroll
    for (int s = 0; s < 4; ++s) {
      const float* f = fb[cur] + s * FS;
      float sj[16], cj[16], k1z[16], k1y[16], k2z[16], k2y[16];
#pragma unroll
      for (int v = 0; v < 4; ++v) {
        *(float4*)&sj[4 * v]  = *(const float4*)(f + i0 + 4 * v);
        *(float4*)&cj[4 * v]  = *(const float4*)(f + 448 + i0 + 4 * v);
        *(float4*)&k1z[4 * v] = *(const float4*)(f + 64 + i0 + 4 * v);
        *(float4*)&k1y[4 * v] = *(const float4*)(f + 128 + i0 + 4 * v);
        *(float4*)&k2z[4 * v] = *(const float4*)(f + 192 + i0 + 4 * v);
        *(float4*)&k2y[4 * v] = *(const float4*)(f + 256 + i0 + 4 * v);
      }
      float4 sc = *(const float4*)(f + 512);   // b1, b2, c12, pad
      float p = 0.f, r2 = 0.f;
#pragma unroll
      for (int j = 0; j < 16; ++j) {
        float s0 = sj[j], c1 = cj[j];
        float z = mz[j], y = my[j];
        float sz = s0 * z;
        z = fmaf(-c1, y, sz);
        y = fmaf(s0, y, 0.1f * sz);
        mz[j] = z; my[j] = y;
        p  = fmaf(k1z[j], z, p);  p  = fmaf(k1y[j], y, p);
        r2 = fmaf(k2z[j], z, r2); r2 = fmaf(k2y[j], y, r2);
      }
      p  += __shfl_xor(p, 1, 64);  p  += __shfl_xor(p, 2, 64);
      r2 += __shfl_xor(r2, 1, 64); r2 += __shfl_xor(r2, 2, 64);
      float e1 = sc.x * p;
      float e2 = sc.y * fmaf(-sc.z, e1, r2);
#pragma unroll
      for (int j = 0; j < 16; ++j) {
        float z = fmaf(-e1, k1z[j], mz[j]);
        mz[j] = fmaf(-e2, k2z[j], z);
        float y = fmaf(-e1, k1y[j], my[j]);
        my[j] = fmaf(-e2, k2y[j], y);
      }
    }
    if (g < 15) {
      ((float4*)fb[1 - cur])[tid] = pf0;
      if (has2) ((float4*)fb[1 - cur])[tid + 512] = pf1;
    }
    __syncthreads();
  }
  float* dst = Mc + ((size_t)cid * 128 + col) * 128;
#pragma unroll
  for (int v = 0; v < 4; ++v)
    *(float4*)(dst + i0 + 4 * v) = *(float4*)&mz[4 * v];
#pragma unroll
  for (int v = 0; v < 4; ++v)
    *(float4*)(dst + 64 + i0 + 4 * v) = *(float4*)&my[4 * v];
}

// offset column d_c: affine replay from h=0, one wave per chunk
__global__ __launch_bounds__(64) void scanB0(
    const float* __restrict__ Feat, float* __restrict__ dc) {
  const int cid = blockIdx.x;
  const int lane = threadIdx.x;
  float z = 0.f, y = 0.f;
  const int t0 = (cid >> 5) * TT + (cid & 31) * LCH;
  for (int t = t0; t < t0 + LCH; ++t) {
    const float* __restrict__ f = Feat + (size_t)t * FS;
    float s = f[lane], c1 = f[448 + lane];
    float k1z = f[64 + lane], k1y = f[128 + lane];
    float k2z = f[192 + lane], k2y = f[256 + lane];
    float bz = f[320 + lane], by = f[384 + lane];
    float b1 = f[512], b2 = f[513], c12 = f[514];
    float sz = s * z;
    float zn = fmaf(-c1, y, sz);
    float yn = fmaf(s, y, 0.1f * sz);
    float p = fmaf(k1y, yn, k1z * zn);
    float qq = fmaf(k2y, yn, k2z * zn);
#pragma unroll
    for (int off = 32; off > 0; off >>= 1) {
      p += __shfl_xor(p, off, 64);
      qq += __shfl_xor(qq, off, 64);
    }
    float e1 = b1 * p;
    float d2 = fmaf(-c12, e1, qq);
    float e2 = b2 * d2;
    z = fmaf(-e1, k1z, zn); z = fmaf(-e2, k2z, z); z += bz;
    y = fmaf(-e1, k1y, yn); y = fmaf(-e2, k2y, y); y += by;
  }
  dc[(size_t)cid * 128 + lane] = z;
  dc[(size_t)cid * 128 + 64 + lane] = y;
}

// sequential chunk combine: h <- M_c h + d_c, store h at chunk starts
__global__ __launch_bounds__(256) void scanB2(
    const float* __restrict__ Mc, const float* __restrict__ dc,
    float* __restrict__ hstart) {
  const int b = blockIdx.x;
  const int tid = threadIdx.x;
  const int i = tid & 127, jh = tid >> 7;
  __shared__ float h[128];
  __shared__ float red[2][128];
  if (tid < 128) h[tid] = 0.f;
  __syncthreads();
  float mreg[64];
  {
    const float* M0 = Mc + (size_t)(b * CH) * 16384;
#pragma unroll
    for (int j = 0; j < 64; ++j) mreg[j] = M0[(size_t)(jh * 64 + j) * 128 + i];
  }
  for (int c = 0; c < CH; ++c) {
    if (tid < 128) hstart[(size_t)(b * CH + c) * 128 + tid] = h[tid];
    float acc = 0.f;
#pragma unroll
    for (int j = 0; j < 64; ++j) acc = fmaf(mreg[j], h[jh * 64 + j], acc);
    red[jh][i] = acc;
    if (c + 1 < CH) {
      const float* Mn = Mc + (size_t)(b * CH + c + 1) * 16384;
#pragma unroll
      for (int j = 0; j < 64; ++j) mreg[j] = Mn[(size_t)(jh * 64 + j) * 128 + i];
    }
    __syncthreads();
    if (tid < 128)
      h[tid] = red[0][tid] + red[1][tid] + dc[(size_t)(b * CH + c) * 128 + tid];
    __syncthreads();
  }
}

// replay within chunk from h_start, one wave per chunk, write hs
__global__ __launch_bounds__(64) void scanB3(
    const float* __restrict__ Feat, const float* __restrict__ hstart,
    float* __restrict__ hs) {
  const int cid = blockIdx.x;
  const int lane = threadIdx.x;
  float z = hstart[(size_t)cid * 128 + lane];
  float y = hstart[(size_t)cid * 128 + 64 + lane];
  const int t0 = (cid >> 5) * TT + (cid & 31) * LCH;
  for (int t = t0; t < t0 + LCH; ++t) {
    const float* __restrict__ f = Feat + (size_t)t * FS;
    float s = f[lane], c1 = f[448 + lane];
    float k1z = f[64 + lane], k1y = f[128 + lane];
    float k2z = f[192 + lane], k2y = f[256 + lane];
    float bz = f[320 + lane], by = f[384 + lane];
    float b1 = f[512], b2 = f[513], c12 = f[514];
    float sz = s * z;
    float zn = fmaf(-c1, y, sz);
    float yn = fmaf(s, y, 0.1f * sz);
    float p = fmaf(k1y, yn, k1z * zn);
    float qq = fmaf(k2y, yn, k2z * zn);
#pragma unroll
    for (int off = 32; off > 0; off >>= 1) {
      p += __shfl_xor(p, off, 64);
      qq += __shfl_xor(qq, off, 64);
    }
    float e1 = b1 * p;
    float d2 = fmaf(-c12, e1, qq);
    float e2 = b2 * d2;
    zn = fmaf(-e1, k1z, zn); zn = fmaf(-e2, k2z, zn); zn += bz;
    yn = fmaf(-e1, k1y, yn); yn = fmaf(-e2, k2y, yn); yn += by;
    hs[(size_t)t * 128 + lane] = zn;
    hs[(size_t)t * 128 + 64 + lane] = yn;
    z = zn; y = yn;
  }
}

// out = hs @ C^T + u*D : tile 64 tokens x 64 dims, K=128 in 2 halves.
__global__ __launch_bounds__(256) void gemmC(
    const float* __restrict__ hs, const float* __restrict__ CmT,
    const float* __restrict__ u, const float* __restrict__ Dv,
    float* __restrict__ out) {
  __shared__ float as2[64][68];
  __shared__ float bs[64][68];
  const int tid = threadIdx.x;
  const int tx = tid & 15, ty = tid >> 4;
  const int t0 = blockIdx.x * 64;
  const int d0 = blockIdx.y * 64;
  float acc[4][4];
#pragma unroll
  for (int i = 0; i < 4; ++i)
#pragma unroll
    for (int j = 0; j < 4; ++j) acc[i][j] = 0.f;

  for (int kb = 0; kb < 128; kb += 64) {
#pragma unroll
    for (int l = 0; l < 4; ++l) {
      int idx = tid + l * 256;
      int r = idx >> 4, c4 = (idx & 15) * 4;
      float4 v = *(const float4*)(hs + (size_t)(t0 + r) * 128 + kb + c4);
      *(float4*)&as2[r][c4] = v;
      float4 w = *(const float4*)(CmT + (size_t)(kb + r) * DM + d0 + c4);
      *(float4*)&bs[r][c4] = w;
    }
    __syncthreads();
#pragma unroll
    for (int k4 = 0; k4 < 16; ++k4) {
      float4 bq0 = *(const float4*)&bs[4 * k4 + 0][tx * 4];
      float4 bq1 = *(const float4*)&bs[4 * k4 + 1][tx * 4];
      float4 bq2 = *(const float4*)&bs[4 * k4 + 2][tx * 4];
      float4 bq3 = *(const float4*)&bs[4 * k4 + 3][tx * 4];
#pragma unroll
      for (int i = 0; i < 4; ++i) {
        float4 a = *(const float4*)&as2[ty * 4 + i][4 * k4];
        acc[i][0] = fmaf(a.x, bq0.x, acc[i][0]);
        acc[i][1] = fmaf(a.x, bq0.y, acc[i][1]);
        acc[i][2] = fmaf(a.x, bq0.z, acc[i][2]);
        acc[i][3] = fmaf(a.x, bq0.w, acc[i][3]);
        acc[i][0] = fmaf(a.y, bq1.x, acc[i][0]);
        acc[i][1] = fmaf(a.y, bq1.y, acc[i][1]);
        acc[i][2] = fmaf(a.y, bq1.z, acc[i][2]);
        acc[i][3] = fmaf(a.y, bq1.w, acc[i][3]);
        acc[i][0] = fmaf(a.z, bq2.x, acc[i][0]);
        acc[i][1] = fmaf(a.z, bq2.y, acc[i][1]);
        acc[i][2] = fmaf(a.z, bq2.z, acc[i][2]);
        acc[i][3] = fmaf(a.z, bq2.w, acc[i][3]);
        acc[i][0] = fmaf(a.w, bq3.x, acc[i][0]);
        acc[i][1] = fmaf(a.w, bq3.y, acc[i][1]);
        acc[i][2] = fmaf(a.w, bq3.z, acc[i][2]);
        acc[i][3] = fmaf(a.w, bq3.w, acc[i][3]);
      }
    }
    __syncthreads();
  }
#pragma unroll
  for (int i = 0; i < 4; ++i) {
    int row = t0 + ty * 4 + i;
    float4 uv = *(const float4*)(u + (size_t)row * DM + d0 + tx * 4);
    float4 dv = *(const float4*)(Dv + d0 + tx * 4);
    float4 o;
    o.x = fmaf(uv.x, dv.x, acc[i][0]);
    o.y = fmaf(uv.y, dv.y, acc[i][1]);
    o.z = fmaf(uv.z, dv.z, acc[i][2]);
    o.w = fmaf(uv.w, dv.w, acc[i][3]);
    *(float4*)(out + (size_t)row * DM + d0 + tx * 4) = o;
  }
}

extern "C" void kernel_launch(void* const* d_in, const int* in_sizes, int n_in,
                              void* d_out, int out_size, void* d_ws, size_t ws_size,
                              hipStream_t stream) {
  const float* u      = (const float*)d_in[0];
  const float* W_A    = (const float*)d_in[1];
  const float* b_A    = (const float*)d_in[2];
  const float* W_k    = (const float*)d_in[3];
  const float* b_k    = (const float*)d_in[4];
  const float* W_beta = (const float*)d_in[5];
  const float* b_beta = (const float*)d_in[6];
  const float* B_w    = (const float*)d_in[7];
  const float* B_b    = (const float*)d_in[8];
  const float* Cm     = (const float*)d_in[9];
  const float* Dv     = (const float*)d_in[10];
  float* out = (float*)d_out;
  char* ws = (char*)d_ws;
  // fixed carve-up (same as 561 µs version)
  float* Wp     = (float*)(ws);                 // 448*1024*4  = 1,835,008
  float* WpT    = (float*)(ws + 1835008);       // legacy slot (fallback only)
  unsigned short* Wb = (unsigned short*)(ws + 1835008);  // 512*1024*2 = 1 MB
  float* CmT    = (float*)(ws + 3670016);       // 128*1024*4 = 524,288
  float* bias   = (float*)(ws + 4194304);       // 450*4 (pad 4096)
  float* Feat   = (float*)(ws + 4198400);       // 16384*520*4 = 34,078,720
  float* Mc     = (float*)(ws + 38277120);      // 256*128*128*4 = 16,777,216
  float* dcv    = (float*)(ws + 55054336);      // 131,072
  float* hstart = (float*)(ws + 55185408);      // 131,072
  float* hsb    = (float*)(ws + 55316480);      // 16384*128*4 = 8,388,608
  // u_hi/u_lo overlay Mc..hsb (written only after gemmA) + extension
  unsigned short* uh = (unsigned short*)(ws + 38277120);  // 33,554,432 B
  unsigned short* ul = (unsigned short*)(ws + 71831552);  // 33,554,432 B
  const size_t NEED1 = 71831552 + 0;            // 1-pass end (uh end)
  const size_t NEED2 = 105385984;               // 2-pass end (ul end)

  packW<<<dim3(448), dim3(256), 0, stream>>>(W_A, b_A, W_k, b_k, b_beta,
                                             B_w, B_b, Wp, bias);
  transK<<<dim3(16, 2), dim3(256), 0, stream>>>(Cm, CmT, DM, 128);

  const bool big1 = (ws_size == 0) || (ws_size >= NEED1);
  const bool big2 = (ws_size == 0) || (ws_size >= NEED2);
  if (big1) {
    const int npass = big2 ? 2 : 1;
    convertW<<<dim3(512), dim3(256), 0, stream>>>(Wp, Wb);
    convertU<<<dim3(16384), dim3(256), 0, stream>>>(u, uh, big2 ? ul : uh);
    gemmA_mfma<<<dim3(128, 4), dim3(256), 0, stream>>>(uh, ul, Wb, Feat, npass);
  } else {
    transK<<<dim3(7, 16), dim3(256), 0, stream>>>(Wp, WpT, NW, DM);
    gemmA_f32<<<dim3(128, 7), dim3(256), 0, stream>>>(u, WpT, Feat);
  }
  postA<<<dim3(16384), dim3(64), 0, stream>>>(Feat, bias, u, W_beta);
  scanB1<<<dim3(256), dim3(512), 0, stream>>>(Feat, Mc);
  scanB0<<<dim3(256), dim3(64), 0, stream>>>(Feat, dcv);
  scanB2<<<dim3(8), dim3(256), 0, stream>>>(Mc, dcv, hstart);
  scanB3<<<dim3(256), dim3(64), 0, stream>>>(Feat, hstart, hsb);
  gemmC<<<dim3(256, 16), dim3(256), 0, stream>>>(hsb, CmT, u, Dv, out);
}

// Round 2
// 423.278 us; speedup vs baseline: 1.3361x; 1.0330x over previous
//
#include <hip/hip_runtime.h>
#include <cmath>

// ---------------------------------------------------------------------------
// OHDeltaProductSSM: u(8,2048,1024) -> out(8,2048,1024), fp32.
// Round 2 change: gemmC (66 us, fp32 VALU, MfmaUtil=0, 41% of vector peak)
// replaced by bf16 MFMA with 3-pass full split precision:
//   out = (hs_hi+hs_lo).(C_hi+C_lo)^T + u*D, computing hh + lh + hl
//   (dropped ll term ~2^-18 relative => absmax unchanged).
// hs_hi/hs_lo are written directly by scanB3 in the tiled swizzled layout
// (same bytes as the old fp32 hs write => neutral for scanB3); C_hi/C_lo by
// a tiny convertC (Cm[d][n] is already the B operand, no transpose).
// All new buffers overlay the dead u_lo region (consumed by gemmA) => no
// workspace growth; convertC ordered after gemmA_mfma.
// Round 1 (kept): gemmA via 2-pass split bf16 MFMA, tiled operands:
//   tile (rowblk, kt) = 128x32 bf16, 8 KB contiguous;
//   element (r,k): g=k>>2, p=g&3, h=g>>2, s' = ((p ^ ((r>>2)&3))<<1)|h,
//   index = r*32 + s'*4 + (k&3). Identical permutation on A and B => the
//   internal-K mapping cancels in the dot product.
// Verified MFMA facts: A row = lane&15, B col = lane&15,
// D: col = lane&15, row = 4*(lane>>4)+reg  [guide m89/m91].
// ---------------------------------------------------------------------------

#define NTOK 16384
#define TT 2048
#define BB 8
#define DM 1024
#define FS 520
#define CH 32
#define LCH 64
#define NW 448   // packed weight rows (valid)
#define NWP 512  // padded for MFMA gemm

typedef short bf16x8 __attribute__((ext_vector_type(8)));
typedef float f32x4 __attribute__((ext_vector_type(4)));

#define GLOAD_LDS16(g, l)                                          \
  __builtin_amdgcn_global_load_lds(                                \
      (const __attribute__((address_space(1))) void*)(g),          \
      (__attribute__((address_space(3))) void*)(l), 16, 0, 0)

__global__ __launch_bounds__(256) void packW(
    const float* __restrict__ W_A, const float* __restrict__ b_A,
    const float* __restrict__ W_k, const float* __restrict__ b_k,
    const float* __restrict__ b_beta,
    const float* __restrict__ B_w, const float* __restrict__ B_b,
    float* __restrict__ Wp, float* __restrict__ bias) {
  int r = blockIdx.x;          // 0..447
  int tid = threadIdx.x;
  const float* src;
  float bv;
  if (r < 64)       { src = W_A + (size_t)r * DM;         bv = b_A[r]; }
  else if (r < 320) { src = W_k + (size_t)(r - 64) * DM;  bv = b_k[r - 64]; }
  else              { src = B_w + (size_t)(r - 320) * DM; bv = B_b[r - 320]; }
  ((float4*)(Wp + (size_t)r * DM))[tid] = ((const float4*)src)[tid];
  if (tid == 0) bias[r] = bv;
  if (r == 0 && tid < 2) bias[448 + tid] = b_beta[tid];
}

// generic transpose: src[M][N] -> dst[N][M], 64x64 tiles, M,N multiples of 64
__global__ __launch_bounds__(256) void transK(
    const float* __restrict__ src, float* __restrict__ dst, int M, int N) {
  __shared__ float tile[64][68];
  const int m0 = blockIdx.x * 64, n0 = blockIdx.y * 64;
  const int tid = threadIdx.x;
#pragma unroll
  for (int l = 0; l < 4; ++l) {
    int idx = tid + l * 256;
    int r = idx >> 4, c4 = (idx & 15) * 4;
    float4 v = *(const float4*)(src + (size_t)(m0 + r) * N + n0 + c4);
    tile[r][c4 + 0] = v.x; tile[r][c4 + 1] = v.y;
    tile[r][c4 + 2] = v.z; tile[r][c4 + 3] = v.w;
  }
  __syncthreads();
#pragma unroll
  for (int l = 0; l < 4; ++l) {
    int idx = tid + l * 256;
    int c = idx >> 4, r4 = (idx & 15) * 4;
    float4 w = make_float4(tile[r4 + 0][c], tile[r4 + 1][c],
                           tile[r4 + 2][c], tile[r4 + 3][c]);
    *(float4*)(dst + (size_t)(n0 + c) * M + m0 + r4) = w;
  }
}

__device__ inline unsigned short bf16_rne(float x) {
  unsigned b = __float_as_uint(x);
  b += 0x7FFFu + ((b >> 16) & 1u);
  return (unsigned short)(b >> 16);
}

__device__ inline void split_bf16(float x, unsigned short& h, unsigned short& l) {
  unsigned b = __float_as_uint(x);
  h = (unsigned short)(b >> 16);                       // truncated high part
  float rem = x - __uint_as_float(b & 0xFFFF0000u);    // exact remainder
  l = bf16_rne(rem);
}

// u fp32 -> u_hi/u_lo bf16, tiled (mb,kt) 128x32, swizzled granules.
__global__ __launch_bounds__(256) void convertU(
    const float* __restrict__ u, unsigned short* __restrict__ uh,
    unsigned short* __restrict__ ul) {
  int gid = blockIdx.x * 256 + threadIdx.x;
  int m = gid >> 8;          // token row 0..16383
  int g = gid & 255;         // granule along k
  float4 v = *(const float4*)(u + (size_t)m * DM + g * 4);
  int kt = g >> 3, gg = g & 7;
  int p = gg & 3, h = gg >> 2;
  int mr = m & 127, mb = m >> 7;
  int pp = p ^ ((mr >> 2) & 3);
  size_t dst = ((size_t)(mb * 32 + kt)) * 4096 + mr * 32 + ((pp << 1) | h) * 4;
  ushort4 hi, lo;
  split_bf16(v.x, hi.x, lo.x);
  split_bf16(v.y, hi.y, lo.y);
  split_bf16(v.z, hi.z, lo.z);
  split_bf16(v.w, hi.w, lo.w);
  *(ushort4*)(uh + dst) = hi;
  *(ushort4*)(ul + dst) = lo;
}

// Wp fp32 (448 rows) -> Wb bf16 tiled (nb,kt) 128x32, rows 448..511 zero.
__global__ __launch_bounds__(256) void convertW(
    const float* __restrict__ Wp, unsigned short* __restrict__ Wb) {
  int gid = blockIdx.x * 256 + threadIdx.x;
  int n = gid >> 8, g = gid & 255;
  int kt = g >> 3, gg = g & 7;
  int p = gg & 3, h = gg >> 2;
  int nr = n & 127, nb = n >> 7;
  int pp = p ^ ((nr >> 2) & 3);
  size_t dst = ((size_t)(nb * 32 + kt)) * 4096 + nr * 32 + ((pp << 1) | h) * 4;
  ushort4 hv = make_ushort4(0, 0, 0, 0);
  if (n < NW) {
    float4 v = *(const float4*)(Wp + (size_t)n * DM + g * 4);
    hv.x = bf16_rne(v.x); hv.y = bf16_rne(v.y);
    hv.z = bf16_rne(v.z); hv.w = bf16_rne(v.w);
  }
  *(ushort4*)(Wb + dst) = hv;
}

// Cm[1024][128] fp32 -> C_hi/C_lo bf16 tiled (nb,kt), nb=d>>7, kt=n>>5.
__global__ __launch_bounds__(256) void convertC(
    const float* __restrict__ Cm, unsigned short* __restrict__ Chp,
    unsigned short* __restrict__ Clp) {
  int gid = blockIdx.x * 256 + threadIdx.x;   // 32768 total
  int d = gid >> 5;          // 0..1023
  int g = gid & 31;          // granule along 128
  float4 v = *(const float4*)(Cm + (size_t)d * 128 + g * 4);
  int kt = g >> 3, gg = g & 7;
  int p = gg & 3, h = gg >> 2;
  int nr = d & 127, nb = d >> 7;
  int pp = p ^ ((nr >> 2) & 3);
  size_t dst = ((size_t)(nb * 4 + kt)) * 4096 + nr * 32 + ((pp << 1) | h) * 4;
  ushort4 hi, lo;
  split_bf16(v.x, hi.x, lo.x);
  split_bf16(v.y, hi.y, lo.y);
  split_bf16(v.z, hi.z, lo.z);
  split_bf16(v.w, hi.w, lo.w);
  *(ushort4*)(Chp + dst) = hi;
  *(ushort4*)(Clp + dst) = lo;
}

// Feat[0..512) = (u_hi + u_lo) . Wb^T via MFMA. 128x128 tile, BK=32,
// 4 waves 2x2, wave tile 64x64 (4x4 fragments of 16x16).
__global__ __launch_bounds__(256) void gemmA_mfma(
    const unsigned short* __restrict__ uh, const unsigned short* __restrict__ ul,
    const unsigned short* __restrict__ Wb, float* __restrict__ Feat, int npass) {
  __shared__ __align__(16) unsigned short As[4096];
  __shared__ __align__(16) unsigned short Bs[4096];
  const int tid = threadIdx.x;
  const int wv = tid >> 6, ln = tid & 63;
  const int lr = ln & 15, G = ln >> 4;
  const int wm = wv >> 1, wn = wv & 1;
  const int x = G ^ (lr >> 2);          // inverse of the granule XOR swizzle
  f32x4 acc[4][4];
#pragma unroll
  for (int i = 0; i < 4; ++i)
#pragma unroll
    for (int j = 0; j < 4; ++j) acc[i][j] = (f32x4){0.f, 0.f, 0.f, 0.f};

  const size_t aBase = (size_t)blockIdx.x * 32 * 4096;
  const size_t bBase = (size_t)blockIdx.y * 32 * 4096;
  const int so = wv * 512 + ln * 8;     // staging src offset (bf16 elems)
  const int ld = wv * 512;              // staging lds base (wave-uniform)

  for (int pass = 0; pass < npass; ++pass) {
    const unsigned short* ua = pass ? ul : uh;
    for (int kt = 0; kt < 32; ++kt) {
      const unsigned short* ga = ua + aBase + (size_t)kt * 4096;
      const unsigned short* gb = Wb + bBase + (size_t)kt * 4096;
      GLOAD_LDS16(ga + so,        As + ld);
      GLOAD_LDS16(ga + 2048 + so, As + 2048 + ld);
      GLOAD_LDS16(gb + so,        Bs + ld);
      GLOAD_LDS16(gb + 2048 + so, Bs + 2048 + ld);
      __syncthreads();
      bf16x8 af[4], bfr[4];
      const char* Ab = (const char*)As + ((wm * 64 + lr) << 6) + (x << 4);
      const char* Bb = (const char*)Bs + ((wn * 64 + lr) << 6) + (x << 4);
#pragma unroll
      for (int i = 0; i < 4; ++i) {
        af[i]  = *(const bf16x8*)(Ab + i * 1024);   // +16 rows = 1024 B
        bfr[i] = *(const bf16x8*)(Bb + i * 1024);
      }
#pragma unroll
      for (int i = 0; i < 4; ++i)
#pragma unroll
        for (int j = 0; j < 4; ++j)
          acc[i][j] = __builtin_amdgcn_mfma_f32_16x16x32_bf16(
              af[i], bfr[j], acc[i][j], 0, 0, 0);
      __syncthreads();
    }
  }
  const int row0 = (blockIdx.x << 7) + wm * 64 + (G << 2);
  const int col0 = (blockIdx.y << 7) + wn * 64 + lr;
  float* fb = Feat + (size_t)row0 * FS + col0;
#pragma unroll
  for (int i = 0; i < 4; ++i)
#pragma unroll
    for (int j = 0; j < 4; ++j) {
      float* d = fb + (size_t)(i * 16) * FS + j * 16;
#pragma unroll
      for (int r = 0; r < 4; ++r) d[(size_t)r * FS] = acc[i][j][r];
    }
}

// out = hs.C^T + u*D via MFMA, 3 passes (hh, lh, hl). K=128, 4 kt tiles.
__global__ __launch_bounds__(256) void gemmC_mfma(
    const unsigned short* __restrict__ hsh, const unsigned short* __restrict__ hsl,
    const unsigned short* __restrict__ Chp, const unsigned short* __restrict__ Clp,
    const float* __restrict__ u, const float* __restrict__ Dv,
    float* __restrict__ out) {
  __shared__ __align__(16) unsigned short As[4096];
  __shared__ __align__(16) unsigned short Bs[4096];
  const int tid = threadIdx.x;
  const int wv = tid >> 6, ln = tid & 63;
  const int lr = ln & 15, G = ln >> 4;
  const int wm = wv >> 1, wn = wv & 1;
  const int x = G ^ (lr >> 2);
  f32x4 acc[4][4];
#pragma unroll
  for (int i = 0; i < 4; ++i)
#pragma unroll
    for (int j = 0; j < 4; ++j) acc[i][j] = (f32x4){0.f, 0.f, 0.f, 0.f};

  const size_t aBase = (size_t)blockIdx.x * 4 * 4096;
  const size_t bBase = (size_t)blockIdx.y * 4 * 4096;
  const int so = wv * 512 + ln * 8;
  const int ld = wv * 512;

#pragma unroll 1
  for (int pass = 0; pass < 3; ++pass) {
    const unsigned short* pa = (pass == 1) ? hsl : hsh;
    const unsigned short* pb = (pass == 2) ? Clp : Chp;
#pragma unroll 1
    for (int kt = 0; kt < 4; ++kt) {
      const unsigned short* ga = pa + aBase + (size_t)kt * 4096;
      const unsigned short* gb = pb + bBase + (size_t)kt * 4096;
      GLOAD_LDS16(ga + so,        As + ld);
      GLOAD_LDS16(ga + 2048 + so, As + 2048 + ld);
      GLOAD_LDS16(gb + so,        Bs + ld);
      GLOAD_LDS16(gb + 2048 + so, Bs + 2048 + ld);
      __syncthreads();
      bf16x8 af[4], bfr[4];
      const char* Ab = (const char*)As + ((wm * 64 + lr) << 6) + (x << 4);
      const char* Bb = (const char*)Bs + ((wn * 64 + lr) << 6) + (x << 4);
#pragma unroll
      for (int i = 0; i < 4; ++i) {
        af[i]  = *(const bf16x8*)(Ab + i * 1024);
        bfr[i] = *(const bf16x8*)(Bb + i * 1024);
      }
#pragma unroll
      for (int i = 0; i < 4; ++i)
#pragma unroll
        for (int j = 0; j < 4; ++j)
          acc[i][j] = __builtin_amdgcn_mfma_f32_16x16x32_bf16(
              af[i], bfr[j], acc[i][j], 0, 0, 0);
      __syncthreads();
    }
  }
  // epilogue: out = acc + u*D. D layout: col=lane&15, row=4*(lane>>4)+reg
  const int row0 = (blockIdx.x << 7) + wm * 64 + (G << 2);
  const int col0 = (blockIdx.y << 7) + wn * 64 + lr;
#pragma unroll
  for (int j = 0; j < 4; ++j) {
    float dv = Dv[col0 + j * 16];
#pragma unroll
    for (int i = 0; i < 4; ++i) {
#pragma unroll
      for (int r = 0; r < 4; ++r) {
        size_t off = (size_t)(row0 + i * 16 + r) * DM + col0 + j * 16;
        out[off] = fmaf(u[off], dv, acc[i][j][r]);
      }
    }
  }
}

// ---- legacy fp32 gemmA (fallback if workspace too small) ------------------
__global__ __launch_bounds__(256) void gemmA_f32(
    const float* __restrict__ u, const float* __restrict__ WpT,
    float* __restrict__ Feat) {
  __shared__ float us2[128][36];
  __shared__ float wsm[32][68];
  const int tid = threadIdx.x;
  const int tx = tid & 15, ty = tid >> 4;
  const int m0 = blockIdx.x * 128;
  const int n0 = blockIdx.y * 64;
  float acc[8][4];
#pragma unroll
  for (int i = 0; i < 8; ++i)
#pragma unroll
    for (int j = 0; j < 4; ++j) acc[i][j] = 0.f;

  for (int k0 = 0; k0 < DM; k0 += 32) {
#pragma unroll
    for (int l = 0; l < 4; ++l) {
      int idx = tid + l * 256;
      int r = idx >> 3, c4 = (idx & 7) * 4;
      float4 v = *(const float4*)(u + (size_t)(m0 + r) * DM + k0 + c4);
      *(float4*)&us2[r][c4] = v;
    }
#pragma unroll
    for (int l = 0; l < 2; ++l) {
      int idx = tid + l * 256;
      int k = idx >> 4, c4 = (idx & 15) * 4;
      float4 v = *(const float4*)(WpT + (size_t)(k0 + k) * NW + n0 + c4);
      *(float4*)&wsm[k][c4] = v;
    }
    __syncthreads();
#pragma unroll
    for (int k4 = 0; k4 < 8; ++k4) {
      float4 bq0 = *(const float4*)&wsm[4 * k4 + 0][tx * 4];
      float4 bq1 = *(const float4*)&wsm[4 * k4 + 1][tx * 4];
      float4 bq2 = *(const float4*)&wsm[4 * k4 + 2][tx * 4];
      float4 bq3 = *(const float4*)&wsm[4 * k4 + 3][tx * 4];
#pragma unroll
      for (int i = 0; i < 8; ++i) {
        float4 a = *(const float4*)&us2[ty * 8 + i][4 * k4];
        acc[i][0] = fmaf(a.x, bq0.x, acc[i][0]);
        acc[i][1] = fmaf(a.x, bq0.y, acc[i][1]);
        acc[i][2] = fmaf(a.x, bq0.z, acc[i][2]);
        acc[i][3] = fmaf(a.x, bq0.w, acc[i][3]);
        acc[i][0] = fmaf(a.y, bq1.x, acc[i][0]);
        acc[i][1] = fmaf(a.y, bq1.y, acc[i][1]);
        acc[i][2] = fmaf(a.y, bq1.z, acc[i][2]);
        acc[i][3] = fmaf(a.y, bq1.w, acc[i][3]);
        acc[i][0] = fmaf(a.z, bq2.x, acc[i][0]);
        acc[i][1] = fmaf(a.z, bq2.y, acc[i][1]);
        acc[i][2] = fmaf(a.z, bq2.z, acc[i][2]);
        acc[i][3] = fmaf(a.z, bq2.w, acc[i][3]);
        acc[i][0] = fmaf(a.w, bq3.x, acc[i][0]);
        acc[i][1] = fmaf(a.w, bq3.y, acc[i][1]);
        acc[i][2] = fmaf(a.w, bq3.z, acc[i][2]);
        acc[i][3] = fmaf(a.w, bq3.w, acc[i][3]);
      }
    }
    __syncthreads();
  }
#pragma unroll
  for (int i = 0; i < 8; ++i) {
    float4 v = make_float4(acc[i][0], acc[i][1], acc[i][2], acc[i][3]);
    *(float4*)(Feat + (size_t)(m0 + ty * 8 + i) * FS + n0 + tx * 4) = v;
  }
}

__device__ inline float wave_sum(float v) {
#pragma unroll
  for (int off = 32; off > 0; off >>= 1) v += __shfl_xor(v, off, 64);
  return v;
}

// per-token nonlinearity, one wave per token, in-place in Feat
__global__ __launch_bounds__(64) void postA(float* __restrict__ Feat,
                                            const float* __restrict__ bias,
                                            const float* __restrict__ u,
                                            const float* __restrict__ Wb) {
  const int t = blockIdx.x, lane = threadIdx.x;
  float* f = Feat + (size_t)t * FS;
  float s0 = 0.f, s1 = 0.f;
#pragma unroll
  for (int j = 0; j < 4; ++j) {
    float4 uv = *(const float4*)(u + (size_t)t * DM + j * 256 + lane * 4);
    float4 w0 = *(const float4*)(Wb + j * 256 + lane * 4);
    float4 w1 = *(const float4*)(Wb + DM + j * 256 + lane * 4);
    s0 = fmaf(uv.x, w0.x, s0); s0 = fmaf(uv.y, w0.y, s0);
    s0 = fmaf(uv.z, w0.z, s0); s0 = fmaf(uv.w, w0.w, s0);
    s1 = fmaf(uv.x, w1.x, s1); s1 = fmaf(uv.y, w1.y, s1);
    s1 = fmaf(uv.z, w1.z, s1); s1 = fmaf(uv.w, w1.w, s1);
  }
  s0 = wave_sum(s0); s1 = wave_sum(s1);
  float a = f[lane] + bias[lane];
  a = fminf(fmaxf(a, 0.f), 100.f);
  float S = 1.f / (1.f + 0.01f * a);
  f[lane] = S;
  f[448 + lane] = 0.1f * a * S;
  float k10 = f[64 + lane] + bias[64 + lane];
  float k11 = f[128 + lane] + bias[128 + lane];
  float n1 = wave_sum(k10 * k10 + k11 * k11);
  float inv1 = 1.f / fmaxf(sqrtf(n1), 1e-12f);
  k10 *= inv1; k11 *= inv1;
  f[64 + lane] = k10; f[128 + lane] = k11;
  float k20 = f[192 + lane] + bias[192 + lane];
  float k21 = f[256 + lane] + bias[256 + lane];
  float n2 = wave_sum(k20 * k20 + k21 * k21);
  float inv2 = 1.f / fmaxf(sqrtf(n2), 1e-12f);
  k20 *= inv2; k21 *= inv2;
  f[192 + lane] = k20; f[256 + lane] = k21;
  float c12 = wave_sum(k10 * k20 + k11 * k21);
  if (lane == 0) {
    f[512] = 2.f / (1.f + expf(-(s0 + bias[448])));
    f[513] = 2.f / (1.f + expf(-(s1 + bias[449])));
    f[514] = c12;
  }
  f[320 + lane] += bias[320 + lane];
  f[384 + lane] += bias[384 + lane];
}

// chunk transition matrices. 512 threads: col = tid>>2, quarter q = tid&3.
__global__ __launch_bounds__(512, 2) void scanB1(
    const float* __restrict__ Feat, float* __restrict__ Mc) {
  const int cid = blockIdx.x;              // 0..255 = b*32 + chunk
  const int t0 = (cid >> 5) * TT + (cid & 31) * LCH;
  const int tid = threadIdx.x;
  const int col = tid >> 2, q = tid & 3;
  const int i0 = q * 16;
  __shared__ float fb[2][4 * FS];
  float mz[16], my[16];
#pragma unroll
  for (int j = 0; j < 16; ++j) {
    mz[j] = (i0 + j == col) ? 1.f : 0.f;
    my[j] = (64 + i0 + j == col) ? 1.f : 0.f;
  }
  {
    const float4* src = (const float4*)(Feat + (size_t)t0 * FS);
    for (int v = tid; v < FS; v += 512) ((float4*)fb[0])[v] = src[v];
  }
  __syncthreads();
  for (int g = 0; g < 16; ++g) {
    const int cur = g & 1;
    float4 pf0, pf1;
    const bool has2 = tid < (FS - 512);
    if (g < 15) {
      const float4* src = (const float4*)(Feat + (size_t)(t0 + (g + 1) * 4) * FS);
      pf0 = src[tid];
      if (has2) pf1 = src[tid + 512];
    }
#pragma unroll
    for (int s = 0; s < 4; ++s) {
      const float* f = fb[cur] + s * FS;
      float sj[16], cj[16], k1z[16], k1y[16], k2z[16], k2y[16];
#pragma unroll
      for (int v = 0; v < 4; ++v) {
        *(float4*)&sj[4 * v]  = *(const float4*)(f + i0 + 4 * v);
        *(float4*)&cj[4 * v]  = *(const float4*)(f + 448 + i0 + 4 * v);
        *(float4*)&k1z[4 * v] = *(const float4*)(f + 64 + i0 + 4 * v);
        *(float4*)&k1y[4 * v] = *(const float4*)(f + 128 + i0 + 4 * v);
        *(float4*)&k2z[4 * v] = *(const float4*)(f + 192 + i0 + 4 * v);
        *(float4*)&k2y[4 * v] = *(const float4*)(f + 256 + i0 + 4 * v);
      }
      float4 sc = *(const float4*)(f + 512);   // b1, b2, c12, pad
      float p = 0.f, r2 = 0.f;
#pragma unroll
      for (int j = 0; j < 16; ++j) {
        float s0 = sj[j], c1 = cj[j];
        float z = mz[j], y = my[j];
        float sz = s0 * z;
        z = fmaf(-c1, y, sz);
        y = fmaf(s0, y, 0.1f * sz);
        mz[j] = z; my[j] = y;
        p  = fmaf(k1z[j], z, p);  p  = fmaf(k1y[j], y, p);
        r2 = fmaf(k2z[j], z, r2); r2 = fmaf(k2y[j], y, r2);
      }
      p  += __shfl_xor(p, 1, 64);  p  += __shfl_xor(p, 2, 64);
      r2 += __shfl_xor(r2, 1, 64); r2 += __shfl_xor(r2, 2, 64);
      float e1 = sc.x * p;
      float e2 = sc.y * fmaf(-sc.z, e1, r2);
#pragma unroll
      for (int j = 0; j < 16; ++j) {
        float z = fmaf(-e1, k1z[j], mz[j]);
        mz[j] = fmaf(-e2, k2z[j], z);
        float y = fmaf(-e1, k1y[j], my[j]);
        my[j] = fmaf(-e2, k2y[j], y);
      }
    }
    if (g < 15) {
      ((float4*)fb[1 - cur])[tid] = pf0;
      if (has2) ((float4*)fb[1 - cur])[tid + 512] = pf1;
    }
    __syncthreads();
  }
  float* dst = Mc + ((size_t)cid * 128 + col) * 128;
#pragma unroll
  for (int v = 0; v < 4; ++v)
    *(float4*)(dst + i0 + 4 * v) = *(float4*)&mz[4 * v];
#pragma unroll
  for (int v = 0; v < 4; ++v)
    *(float4*)(dst + 64 + i0 + 4 * v) = *(float4*)&my[4 * v];
}

// offset column d_c: affine replay from h=0, one wave per chunk
__global__ __launch_bounds__(64) void scanB0(
    const float* __restrict__ Feat, float* __restrict__ dc) {
  const int cid = blockIdx.x;
  const int lane = threadIdx.x;
  float z = 0.f, y = 0.f;
  const int t0 = (cid >> 5) * TT + (cid & 31) * LCH;
  for (int t = t0; t < t0 + LCH; ++t) {
    const float* __restrict__ f = Feat + (size_t)t * FS;
    float s = f[lane], c1 = f[448 + lane];
    float k1z = f[64 + lane], k1y = f[128 + lane];
    float k2z = f[192 + lane], k2y = f[256 + lane];
    float bz = f[320 + lane], by = f[384 + lane];
    float b1 = f[512], b2 = f[513], c12 = f[514];
    float sz = s * z;
    float zn = fmaf(-c1, y, sz);
    float yn = fmaf(s, y, 0.1f * sz);
    float p = fmaf(k1y, yn, k1z * zn);
    float qq = fmaf(k2y, yn, k2z * zn);
#pragma unroll
    for (int off = 32; off > 0; off >>= 1) {
      p += __shfl_xor(p, off, 64);
      qq += __shfl_xor(qq, off, 64);
    }
    float e1 = b1 * p;
    float d2 = fmaf(-c12, e1, qq);
    float e2 = b2 * d2;
    z = fmaf(-e1, k1z, zn); z = fmaf(-e2, k2z, z); z += bz;
    y = fmaf(-e1, k1y, yn); y = fmaf(-e2, k2y, y); y += by;
  }
  dc[(size_t)cid * 128 + lane] = z;
  dc[(size_t)cid * 128 + 64 + lane] = y;
}

// sequential chunk combine: h <- M_c h + d_c, store h at chunk starts
__global__ __launch_bounds__(256) void scanB2(
    const float* __restrict__ Mc, const float* __restrict__ dc,
    float* __restrict__ hstart) {
  const int b = blockIdx.x;
  const int tid = threadIdx.x;
  const int i = tid & 127, jh = tid >> 7;
  __shared__ float h[128];
  __shared__ float red[2][128];
  if (tid < 128) h[tid] = 0.f;
  __syncthreads();
  float mreg[64];
  {
    const float* M0 = Mc + (size_t)(b * CH) * 16384;
#pragma unroll
    for (int j = 0; j < 64; ++j) mreg[j] = M0[(size_t)(jh * 64 + j) * 128 + i];
  }
  for (int c = 0; c < CH; ++c) {
    if (tid < 128) hstart[(size_t)(b * CH + c) * 128 + tid] = h[tid];
    float acc = 0.f;
#pragma unroll
    for (int j = 0; j < 64; ++j) acc = fmaf(mreg[j], h[jh * 64 + j], acc);
    red[jh][i] = acc;
    if (c + 1 < CH) {
      const float* Mn = Mc + (size_t)(b * CH + c + 1) * 16384;
#pragma unroll
      for (int j = 0; j < 64; ++j) mreg[j] = Mn[(size_t)(jh * 64 + j) * 128 + i];
    }
    __syncthreads();
    if (tid < 128)
      h[tid] = red[0][tid] + red[1][tid] + dc[(size_t)(b * CH + c) * 128 + tid];
    __syncthreads();
  }
}

// replay within chunk from h_start, one wave per chunk.
// split=1: write hs_hi/hs_lo bf16 in tiled swizzled layout (for gemmC_mfma)
// split=0: write fp32 hs (fallback gemmC path)
__global__ __launch_bounds__(64) void scanB3(
    const float* __restrict__ Feat, const float* __restrict__ hstart,
    float* __restrict__ hs, unsigned short* __restrict__ hsh,
    unsigned short* __restrict__ hsl, int split) {
  const int cid = blockIdx.x;
  const int lane = threadIdx.x;
  float z = hstart[(size_t)cid * 128 + lane];
  float y = hstart[(size_t)cid * 128 + 64 + lane];
  const int t0 = (cid >> 5) * TT + (cid & 31) * LCH;
  // per-lane k decomposition for split writes (z: k=lane, y: k=64+lane)
  const int ktz = lane >> 5, kkz = lane & 31;
  const int kty = (64 + lane) >> 5, kky = lane & 31;
  const int pz = (kkz >> 2) & 3, hz = kkz >> 4;
  const int lowz = kkz & 3;
  for (int t = t0; t < t0 + LCH; ++t) {
    const float* __restrict__ f = Feat + (size_t)t * FS;
    float s = f[lane], c1 = f[448 + lane];
    float k1z = f[64 + lane], k1y = f[128 + lane];
    float k2z = f[192 + lane], k2y = f[256 + lane];
    float bz = f[320 + lane], by = f[384 + lane];
    float b1 = f[512], b2 = f[513], c12 = f[514];
    float sz = s * z;
    float zn = fmaf(-c1, y, sz);
    float yn = fmaf(s, y, 0.1f * sz);
    float p = fmaf(k1y, yn, k1z * zn);
    float qq = fmaf(k2y, yn, k2z * zn);
#pragma unroll
    for (int off = 32; off > 0; off >>= 1) {
      p += __shfl_xor(p, off, 64);
      qq += __shfl_xor(qq, off, 64);
    }
    float e1 = b1 * p;
    float d2 = fmaf(-c12, e1, qq);
    float e2 = b2 * d2;
    zn = fmaf(-e1, k1z, zn); zn = fmaf(-e2, k2z, zn); zn += bz;
    yn = fmaf(-e1, k1y, yn); yn = fmaf(-e2, k2y, yn); yn += by;
    if (split) {
      const int mb = t >> 7, mr = t & 127;
      const int xr = (mr >> 2) & 3;
      {
        size_t idx = ((size_t)(mb * 4 + ktz)) * 4096 + mr * 32 +
                     ((((pz ^ xr) << 1) | hz)) * 4 + lowz;
        unsigned short hi, lo;
        split_bf16(zn, hi, lo);
        hsh[idx] = hi; hsl[idx] = lo;
      }
      {
        size_t idx = ((size_t)(mb * 4 + kty)) * 4096 + mr * 32 +
                     ((((pz ^ xr) << 1) | hz)) * 4 + lowz;   // same kk pattern
        unsigned short hi, lo;
        split_bf16(yn, hi, lo);
        hsh[idx] = hi; hsl[idx] = lo;
      }
    } else {
      hs[(size_t)t * 128 + lane] = zn;
      hs[(size_t)t * 128 + 64 + lane] = yn;
    }
    z = zn; y = yn;
  }
  (void)kky;
}

// legacy fp32 gemmC (fallback)
__global__ __launch_bounds__(256) void gemmC(
    const float* __restrict__ hs, const float* __restrict__ CmT,
    const float* __restrict__ u, const float* __restrict__ Dv,
    float* __restrict__ out) {
  __shared__ float as2[64][68];
  __shared__ float bs[64][68];
  const int tid = threadIdx.x;
  const int tx = tid & 15, ty = tid >> 4;
  const int t0 = blockIdx.x * 64;
  const int d0 = blockIdx.y * 64;
  float acc[4][4];
#pragma unroll
  for (int i = 0; i < 4; ++i)
#pragma unroll
    for (int j = 0; j < 4; ++j) acc[i][j] = 0.f;

  for (int kb = 0; kb < 128; kb += 64) {
#pragma unroll
    for (int l = 0; l < 4; ++l) {
      int idx = tid + l * 256;
      int r = idx >> 4, c4 = (idx & 15) * 4;
      float4 v = *(const float4*)(hs + (size_t)(t0 + r) * 128 + kb + c4);
      *(float4*)&as2[r][c4] = v;
      float4 w = *(const float4*)(CmT + (size_t)(kb + r) * DM + d0 + c4);
      *(float4*)&bs[r][c4] = w;
    }
    __syncthreads();
#pragma unroll
    for (int k4 = 0; k4 < 16; ++k4) {
      float4 bq0 = *(const float4*)&bs[4 * k4 + 0][tx * 4];
      float4 bq1 = *(const float4*)&bs[4 * k4 + 1][tx * 4];
      float4 bq2 = *(const float4*)&bs[4 * k4 + 2][tx * 4];
      float4 bq3 = *(const float4*)&bs[4 * k4 + 3][tx * 4];
#pragma unroll
      for (int i = 0; i < 4; ++i) {
        float4 a = *(const float4*)&as2[ty * 4 + i][4 * k4];
        acc[i][0] = fmaf(a.x, bq0.x, acc[i][0]);
        acc[i][1] = fmaf(a.x, bq0.y, acc[i][1]);
        acc[i][2] = fmaf(a.x, bq0.z, acc[i][2]);
        acc[i][3] = fmaf(a.x, bq0.w, acc[i][3]);
        acc[i][0] = fmaf(a.y, bq1.x, acc[i][0]);
        acc[i][1] = fmaf(a.y, bq1.y, acc[i][1]);
        acc[i][2] = fmaf(a.y, bq1.z, acc[i][2]);
        acc[i][3] = fmaf(a.y, bq1.w, acc[i][3]);
        acc[i][0] = fmaf(a.z, bq2.x, acc[i][0]);
        acc[i][1] = fmaf(a.z, bq2.y, acc[i][1]);
        acc[i][2] = fmaf(a.z, bq2.z, acc[i][2]);
        acc[i][3] = fmaf(a.z, bq2.w, acc[i][3]);
        acc[i][0] = fmaf(a.w, bq3.x, acc[i][0]);
        acc[i][1] = fmaf(a.w, bq3.y, acc[i][1]);
        acc[i][2] = fmaf(a.w, bq3.z, acc[i][2]);
        acc[i][3] = fmaf(a.w, bq3.w, acc[i][3]);
      }
    }
    __syncthreads();
  }
#pragma unroll
  for (int i = 0; i < 4; ++i) {
    int row = t0 + ty * 4 + i;
    float4 uv = *(const float4*)(u + (size_t)row * DM + d0 + tx * 4);
    float4 dv = *(const float4*)(Dv + d0 + tx * 4);
    float4 o;
    o.x = fmaf(uv.x, dv.x, acc[i][0]);
    o.y = fmaf(uv.y, dv.y, acc[i][1]);
    o.z = fmaf(uv.z, dv.z, acc[i][2]);
    o.w = fmaf(uv.w, dv.w, acc[i][3]);
    *(float4*)(out + (size_t)row * DM + d0 + tx * 4) = o;
  }
}

extern "C" void kernel_launch(void* const* d_in, const int* in_sizes, int n_in,
                              void* d_out, int out_size, void* d_ws, size_t ws_size,
                              hipStream_t stream) {
  const float* u      = (const float*)d_in[0];
  const float* W_A    = (const float*)d_in[1];
  const float* b_A    = (const float*)d_in[2];
  const float* W_k    = (const float*)d_in[3];
  const float* b_k    = (const float*)d_in[4];
  const float* W_beta = (const float*)d_in[5];
  const float* b_beta = (const float*)d_in[6];
  const float* B_w    = (const float*)d_in[7];
  const float* B_b    = (const float*)d_in[8];
  const float* Cm     = (const float*)d_in[9];
  const float* Dv     = (const float*)d_in[10];
  float* out = (float*)d_out;
  char* ws = (char*)d_ws;
  // fixed carve-up
  float* Wp     = (float*)(ws);                 // 448*1024*4  = 1,835,008
  float* WpT    = (float*)(ws + 1835008);       // legacy slot (fallback only)
  unsigned short* Wb = (unsigned short*)(ws + 1835008);  // 512*1024*2 = 1 MB
  float* CmT    = (float*)(ws + 3670016);       // 128*1024*4 = 524,288
  float* bias   = (float*)(ws + 4194304);       // 450*4 (pad 4096)
  float* Feat   = (float*)(ws + 4198400);       // 16384*520*4 = 34,078,720
  float* Mc     = (float*)(ws + 38277120);      // 256*128*128*4 = 16,777,216
  float* dcv    = (float*)(ws + 55054336);      // 131,072
  float* hstart = (float*)(ws + 55185408);      // 131,072
  float* hsb    = (float*)(ws + 55316480);      // 16384*128*4 = 8,388,608
  // u_hi/u_lo overlay Mc..hsb (written only after gemmA) + extension
  unsigned short* uh = (unsigned short*)(ws + 38277120);  // 33,554,432 B
  unsigned short* ul = (unsigned short*)(ws + 71831552);  // 33,554,432 B
  // gemmC split operands overlay ul (dead after gemmA_mfma pass 2):
  unsigned short* hsh = (unsigned short*)(ws + 71831552); // 4,194,304
  unsigned short* hsl = (unsigned short*)(ws + 76025856); // 4,194,304
  unsigned short* Chp = (unsigned short*)(ws + 80220160); //   262,144
  unsigned short* Clp = (unsigned short*)(ws + 80482304); //   262,144
  const size_t NEED1 = 71831552;                // 1-pass end (uh end)
  const size_t NEED2 = 105385984;               // 2-pass end (ul end)

  packW<<<dim3(448), dim3(256), 0, stream>>>(W_A, b_A, W_k, b_k, b_beta,
                                             B_w, B_b, Wp, bias);
  transK<<<dim3(16, 2), dim3(256), 0, stream>>>(Cm, CmT, DM, 128);

  const bool big1 = (ws_size == 0) || (ws_size >= NEED1);
  const bool big2 = (ws_size == 0) || (ws_size >= NEED2);
  if (big1) {
    const int npass = big2 ? 2 : 1;
    convertW<<<dim3(512), dim3(256), 0, stream>>>(Wp, Wb);
    convertU<<<dim3(16384), dim3(256), 0, stream>>>(u, uh, big2 ? ul : uh);
    gemmA_mfma<<<dim3(128, 4), dim3(256), 0, stream>>>(uh, ul, Wb, Feat, npass);
    if (big2)
      convertC<<<dim3(128), dim3(256), 0, stream>>>(Cm, Chp, Clp);
  } else {
    transK<<<dim3(7, 16), dim3(256), 0, stream>>>(Wp, WpT, NW, DM);
    gemmA_f32<<<dim3(128, 7), dim3(256), 0, stream>>>(u, WpT, Feat);
  }
  postA<<<dim3(16384), dim3(64), 0, stream>>>(Feat, bias, u, W_beta);
  scanB1<<<dim3(256), dim3(512), 0, stream>>>(Feat, Mc);
  scanB0<<<dim3(256), dim3(64), 0, stream>>>(Feat, dcv);
  scanB2<<<dim3(8), dim3(256), 0, stream>>>(Mc, dcv, hstart);
  if (big2) {
    scanB3<<<dim3(256), dim3(64), 0, stream>>>(Feat, hstart, hsb, hsh, hsl, 1);
    gemmC_mfma<<<dim3(128, 8), dim3(256), 0, stream>>>(hsh, hsl, Chp, Clp,
                                                       u, Dv, out);
  } else {
    scanB3<<<dim3(256), dim3(64), 0, stream>>>(Feat, hstart, hsb, hsh, hsl, 0);
    gemmC<<<dim3(256, 16), dim3(256), 0, stream>>>(hsb, CmT, u, Dv, out);
  }
}